// Round 7
// baseline (973.021 us; speedup 1.0000x reference)
//
#include <hip/hip_runtime.h>
#include <hip/hip_bf16.h>
#include <stdint.h>

typedef __hip_bfloat16 bf16;
typedef __attribute__((ext_vector_type(8))) __bf16 bf16x8;
typedef __attribute__((ext_vector_type(4))) float f32x4;

#define D_MODEL 1024
#define NHEAD   16
#define HDIM    64
#define DFF     4096
#define BATCH   16
#define SEQ     512
#define MROWS   (BATCH*SEQ)   // 8192

__device__ __forceinline__ float b2f_bits(unsigned short u) {
    return __uint_as_float(((unsigned)u) << 16);
}
__device__ __forceinline__ bf16 f2b(float v) { return __float2bfloat16(v); }
__device__ __forceinline__ unsigned short f2b_bits(float v) {
    bf16 t = __float2bfloat16(v);
    return *(unsigned short*)&t;
}

// ---------------------------------------------------------------------------
// fp32 -> bf16 weight conversion (n multiple of 4; grid covers exactly n/4)
// ---------------------------------------------------------------------------
__global__ __launch_bounds__(256)
void cvt_kernel(const float* __restrict__ in, bf16* __restrict__ out, int n)
{
    int i = (blockIdx.x * 256 + threadIdx.x) * 4;
    if (i >= n) return;
    float4 f = *(const float4*)(in + i);
    ushort4 o;
    o.x = f2b_bits(f.x); o.y = f2b_bits(f.y);
    o.z = f2b_bits(f.z); o.w = f2b_bits(f.w);
    *(ushort4*)((unsigned short*)out + i) = o;
}

// ---------------------------------------------------------------------------
// LayerNorm: fp32 in, bf16 out. One block (256 threads) per row of 1024.
// ---------------------------------------------------------------------------
__global__ __launch_bounds__(256)
void ln_kernel(const float* __restrict__ xin, const float* __restrict__ w,
               const float* __restrict__ b, bf16* __restrict__ out)
{
    int row  = blockIdx.x;
    int t    = threadIdx.x;
    int lane = t & 63, wv = t >> 6;
    int col  = t * 4;

    float4 f = *(const float4*)(xin + (size_t)row * D_MODEL + col);
    float v[4] = {f.x, f.y, f.z, f.w};

    float s  = v[0] + v[1] + v[2] + v[3];
    float ss = v[0]*v[0] + v[1]*v[1] + v[2]*v[2] + v[3]*v[3];
    #pragma unroll
    for (int m = 1; m < 64; m <<= 1) {
        s  += __shfl_xor(s,  m, 64);
        ss += __shfl_xor(ss, m, 64);
    }
    __shared__ float rs0[4], rs1[4];
    if (lane == 0) { rs0[wv] = s; rs1[wv] = ss; }
    __syncthreads();
    s  = rs0[0] + rs0[1] + rs0[2] + rs0[3];
    ss = rs1[0] + rs1[1] + rs1[2] + rs1[3];

    float mu  = s * (1.0f / D_MODEL);
    float var = ss * (1.0f / D_MODEL) - mu * mu;
    float rs  = rsqrtf(var + 1e-5f);

    float4 wf = *(const float4*)(w + col);
    float4 bf = *(const float4*)(b + col);
    ushort4 o;
    o.x = f2b_bits((v[0]-mu)*rs*wf.x + bf.x);
    o.y = f2b_bits((v[1]-mu)*rs*wf.y + bf.y);
    o.z = f2b_bits((v[2]-mu)*rs*wf.z + bf.z);
    o.w = f2b_bits((v[3]-mu)*rs*wf.w + bf.w);
    *(ushort4*)((unsigned short*)out + (size_t)row * D_MODEL + col) = o;
}

// ---------------------------------------------------------------------------
// MFMA GEMM: C[M,N] = A[M,K] * Bw[N,K]^T + bias (fp32). Epilogues:
//   EPI 0: bias -> out            EPI 1: bias + exact GELU -> out
//   EPI 2: bias + fp32 residual -> out
//   EPI 3: bias -> scatter bf16 Q (b,h,s,e) / KT (b,h,e,s) / V (b,h,s,e)
// OUT_B16: store bf16 (internal buffers) vs fp32 (x1 / d_out).
// 128x128 tile, 256 threads (4 waves 2x2), wave = 4x4 mfma_f32_16x16x32_bf16.
// C/D mapping (m89/m91 verified): col = lane&15, row = (lane>>4)*4 + reg.
// M,N multiples of 128; K multiple of 32.
// ---------------------------------------------------------------------------
template<int EPI, bool OUT_B16>
__global__ __launch_bounds__(256)
void gemm_bt(const bf16* __restrict__ A, const bf16* __restrict__ Bw,
             const float* __restrict__ bias, const float* __restrict__ resid,
             void* __restrict__ Cout, bf16* __restrict__ qb,
             bf16* __restrict__ ktb, bf16* __restrict__ vb,
             int M, int N, int K)
{
    int t    = threadIdx.x;
    int lane = t & 63, w = t >> 6;
    int wm   = w & 1,  wn = w >> 1;
    int q    = lane >> 4, r = lane & 15;
    int mb   = blockIdx.y * 128, nb = blockIdx.x * 128;

    __shared__ __bf16 As[128 * 32];
    __shared__ __bf16 Bs[128 * 32];

    f32x4 acc[4][4] = {};

    const unsigned short* Ag = (const unsigned short*)A + (size_t)mb * K;
    const unsigned short* Bg = (const unsigned short*)Bw + (size_t)nb * K;

    int ar0 = t >> 2,         ac0 = (t & 3) << 3;
    int ar1 = (t + 256) >> 2, ac1 = ((t + 256) & 3) << 3;

    for (int k0 = 0; k0 < K; k0 += 32) {
        int4 a0 = *(const int4*)(Ag + (size_t)ar0 * K + k0 + ac0);
        int4 a1 = *(const int4*)(Ag + (size_t)ar1 * K + k0 + ac1);
        int4 b0 = *(const int4*)(Bg + (size_t)ar0 * K + k0 + ac0);
        int4 b1 = *(const int4*)(Bg + (size_t)ar1 * K + k0 + ac1);
        __syncthreads();
        *(int4*)(As + ar0 * 32 + ac0) = a0;
        *(int4*)(As + ar1 * 32 + ac1) = a1;
        *(int4*)(Bs + ar0 * 32 + ac0) = b0;
        *(int4*)(Bs + ar1 * 32 + ac1) = b1;
        __syncthreads();

        bf16x8 af[4], bfr[4];
        #pragma unroll
        for (int i = 0; i < 4; i++)
            af[i] = *(const bf16x8*)(As + (wm * 64 + i * 16 + r) * 32 + q * 8);
        #pragma unroll
        for (int j = 0; j < 4; j++)
            bfr[j] = *(const bf16x8*)(Bs + (wn * 64 + j * 16 + r) * 32 + q * 8);
        #pragma unroll
        for (int i = 0; i < 4; i++)
            #pragma unroll
            for (int j = 0; j < 4; j++)
                acc[i][j] = __builtin_amdgcn_mfma_f32_16x16x32_bf16(af[i], bfr[j], acc[i][j], 0, 0, 0);
    }

    #pragma unroll
    for (int j = 0; j < 4; j++) {
        int n = nb + wn * 64 + j * 16 + r;
        float bv = bias[n];
        #pragma unroll
        for (int i = 0; i < 4; i++) {
            int mbase = mb + wm * 64 + i * 16 + q * 4;
            #pragma unroll
            for (int rr = 0; rr < 4; rr++) {
                int m = mbase + rr;
                float v = acc[i][j][rr] + bv;
                if (EPI == 1) v = 0.5f * v * (1.0f + erff(v * 0.70710678118654752f));
                if (EPI == 2) v += resid[(size_t)m * N + n];
                if (EPI == 3) {
                    int sect = n >> 10;
                    int h = (n >> 6) & 15;
                    int e = n & 63;
                    int bi = m >> 9, s = m & 511;
                    size_t bh = (size_t)bi * NHEAD + h;
                    bf16 val = f2b(v);
                    if (sect == 0)      qb[((bh * SEQ + s) << 6) + e] = val;
                    else if (sect == 1) ktb[((bh * HDIM + e) << 9) + s] = val;
                    else                vb[((bh * SEQ + s) << 6) + e] = val;
                } else {
                    if (OUT_B16) ((bf16*)Cout)[(size_t)m * N + n] = f2b(v);
                    else         ((float*)Cout)[(size_t)m * N + n] = v;
                }
            }
        }
    }
}

// ---------------------------------------------------------------------------
// Attention: block = (b,h, 16 query rows), 4 waves, wave = 4 rows.
// Q (b,h,s,e), KT (b,h,e,s), V (b,h,s,e) bf16; relb fp32.
// scores = (Q*0.125).KT + rel_bias ; fp32 softmax ; out = P V -> (b,s,h*64+e) bf16.
// ---------------------------------------------------------------------------
__global__ __launch_bounds__(256)
void attn_kernel(const bf16* __restrict__ Q, const bf16* __restrict__ KT,
                 const bf16* __restrict__ V, const float* __restrict__ relb,
                 bf16* __restrict__ out)
{
    int bh = blockIdx.y;
    int b  = bh >> 4, h = bh & 15;
    int q0 = blockIdx.x * 16;
    int t = threadIdx.x, lane = t & 63, w = t >> 6;

    __shared__ float qs[16][64];
    __shared__ float Ps[16][512];

    {   // load 16 q rows, pre-scaled by 1/sqrt(64)
        int rrow = t >> 4;
        int e0   = (t & 15) * 4;
        const unsigned short* qp = (const unsigned short*)Q
            + (((size_t)bh * SEQ + q0 + rrow) << 6) + e0;
        ushort4 u = *(const ushort4*)qp;
        qs[rrow][e0 + 0] = 0.125f * b2f_bits(u.x);
        qs[rrow][e0 + 1] = 0.125f * b2f_bits(u.y);
        qs[rrow][e0 + 2] = 0.125f * b2f_bits(u.z);
        qs[rrow][e0 + 3] = 0.125f * b2f_bits(u.w);
    }
    __syncthreads();

    int r0 = w * 4;
    const unsigned* KTu = (const unsigned*)KT + (size_t)bh * HDIM * (SEQ / 2);

    float sacc[4][4][2] = {};
    for (int e = 0; e < 64; e++) {
        const unsigned* rowp = KTu + (size_t)e * (SEQ / 2) + lane;
        unsigned u0 = rowp[0], u1 = rowp[64], u2 = rowp[128], u3 = rowp[192];
        float kl[4], kh[4];
        kl[0] = __uint_as_float(u0 << 16); kh[0] = __uint_as_float(u0 & 0xffff0000u);
        kl[1] = __uint_as_float(u1 << 16); kh[1] = __uint_as_float(u1 & 0xffff0000u);
        kl[2] = __uint_as_float(u2 << 16); kh[2] = __uint_as_float(u2 & 0xffff0000u);
        kl[3] = __uint_as_float(u3 << 16); kh[3] = __uint_as_float(u3 & 0xffff0000u);
        #pragma unroll
        for (int r = 0; r < 4; r++) {
            float qe = qs[r0 + r][e];
            #pragma unroll
            for (int i = 0; i < 4; i++) {
                sacc[r][i][0] += qe * kl[i];
                sacc[r][i][1] += qe * kh[i];
            }
        }
    }

    float rcp[4];
    const float* rb = relb + (size_t)h * (2 * SEQ - 1);
    #pragma unroll
    for (int r = 0; r < 4; r++) {
        int qa = q0 + r0 + r;
        float mx = -1e30f;
        float sv[4][2];
        #pragma unroll
        for (int i = 0; i < 4; i++)
            #pragma unroll
            for (int c = 0; c < 2; c++) {
                int kk  = 2 * (lane + 64 * i) + c;
                int rel = qa - kk + (SEQ - 1);      // in [0, 1022]
                float s = sacc[r][i][c] + rb[rel];
                sv[i][c] = s;
                mx = fmaxf(mx, s);
            }
        #pragma unroll
        for (int m = 1; m < 64; m <<= 1) mx = fmaxf(mx, __shfl_xor(mx, m, 64));
        float sum = 0.0f;
        #pragma unroll
        for (int i = 0; i < 4; i++)
            #pragma unroll
            for (int c = 0; c < 2; c++) {
                float p = __expf(sv[i][c] - mx);
                sum += p;
                Ps[r0 + r][2 * (lane + 64 * i) + c] = p;
            }
        #pragma unroll
        for (int m = 1; m < 64; m <<= 1) sum += __shfl_xor(sum, m, 64);
        rcp[r] = 1.0f / sum;
    }
    __syncthreads();

    int e = lane;
    const unsigned short* Vb = (const unsigned short*)V + ((size_t)bh * SEQ << 6) + e;
    float acc[4] = {0.f, 0.f, 0.f, 0.f};
    for (int k = 0; k < SEQ; k += 4) {
        float vf0 = b2f_bits(Vb[(size_t)(k + 0) << 6]);
        float vf1 = b2f_bits(Vb[(size_t)(k + 1) << 6]);
        float vf2 = b2f_bits(Vb[(size_t)(k + 2) << 6]);
        float vf3 = b2f_bits(Vb[(size_t)(k + 3) << 6]);
        #pragma unroll
        for (int r = 0; r < 4; r++) {
            float4 p = *(const float4*)&Ps[r0 + r][k];
            acc[r] += p.x * vf0 + p.y * vf1 + p.z * vf2 + p.w * vf3;
        }
    }
    bf16* op = out + ((size_t)(b * SEQ + q0 + r0)) * D_MODEL + h * HDIM + e;
    #pragma unroll
    for (int r = 0; r < 4; r++)
        op[(size_t)r * D_MODEL] = f2b(acc[r] * rcp[r]);
}

// ---------------------------------------------------------------------------
// Launch. Inputs fp32 (dict order), OUTPUT fp32 (reference dtype).
// ws peak 105 MiB (ws >= 128 MiB established: R1/R3 ran 120-128 MiB cleanly):
//   [0,1):    unused
//   [1,7)     wqkv_b     [7,9) wo_b
//   [9,25)    xn -> xn2  (sequential liveness)
//   [25,41)   Q  \
//   [41,57)   KT  } -> x1 fp32 [25,57) after attention
//   [57,65)   w1_b       [65,73) w2_b
//   [73,105)  hid bf16 4096x4096 chunk
// d_out (32 MiB fp32) doubles as scratch before final writes:
//   V bf16 = d_out[0,16M), att bf16 = d_out[16M,32M)
// ---------------------------------------------------------------------------
extern "C" void kernel_launch(void* const* d_in, const int* in_sizes, int n_in,
                              void* d_out, int out_size, void* d_ws, size_t ws_size,
                              hipStream_t stream)
{
    const float* x    = (const float*)d_in[0];
    const float* wqkv = (const float*)d_in[1];
    const float* bqkv = (const float*)d_in[2];
    const float* wo   = (const float*)d_in[3];
    const float* bo   = (const float*)d_in[4];
    const float* relb = (const float*)d_in[5];
    const float* w1   = (const float*)d_in[6];
    const float* b1   = (const float*)d_in[7];
    const float* w2   = (const float*)d_in[8];
    const float* b2   = (const float*)d_in[9];
    const float* ln1w = (const float*)d_in[10];
    const float* ln1b = (const float*)d_in[11];
    const float* ln2w = (const float*)d_in[12];
    const float* ln2b = (const float*)d_in[13];

    char* ws = (char*)d_ws;
    const size_t MB = 1048576;
    bf16*  wqkv_b = (bf16*)(ws + 1 * MB);
    bf16*  wo_b   = (bf16*)(ws + 7 * MB);
    bf16*  xn     = (bf16*)(ws + 9 * MB);
    bf16*  Q      = (bf16*)(ws + 25 * MB);
    bf16*  KT     = (bf16*)(ws + 41 * MB);
    float* x1     = (float*)(ws + 25 * MB);  // over dead Q+KT, 32 MiB
    bf16*  w1_b   = (bf16*)(ws + 57 * MB);
    bf16*  w2_b   = (bf16*)(ws + 65 * MB);
    bf16*  xn2    = (bf16*)(ws + 9 * MB);    // over dead xn
    bf16*  hid    = (bf16*)(ws + 73 * MB);   // 4096x4096 bf16 chunk
    bf16*  V      = (bf16*)d_out;                       // d_out[0,16M)
    bf16*  att    = (bf16*)((char*)d_out + 16 * MB);    // d_out[16M,32M)
    float* out    = (float*)d_out;

    // 1. all weights fp32 -> bf16
    cvt_kernel<<<3072, 256, 0, stream>>>(wqkv, wqkv_b, 3 * D_MODEL * D_MODEL);
    cvt_kernel<<<1024, 256, 0, stream>>>(wo,   wo_b,   D_MODEL * D_MODEL);
    cvt_kernel<<<4096, 256, 0, stream>>>(w1,   w1_b,   DFF * D_MODEL);
    cvt_kernel<<<4096, 256, 0, stream>>>(w2,   w2_b,   D_MODEL * DFF);
    // 2. xn = LN1(x)
    ln_kernel<<<MROWS, 256, 0, stream>>>(x, ln1w, ln1b, xn);
    // 3. qkv projection scattered into Q / KT / V(=d_out scratch)
    gemm_bt<3,true><<<dim3(24, 64), 256, 0, stream>>>(xn, wqkv_b, bqkv, nullptr,
        nullptr, Q, KT, V, MROWS, 3 * D_MODEL, D_MODEL);
    // 4. attention -> att (d_out scratch, bf16)
    attn_kernel<<<dim3(32, 256), 256, 0, stream>>>(Q, KT, V, relb, att);
    // 5. x1 = x + att @ Wo^T + bo   (fp32, over dead Q+KT)
    gemm_bt<2,false><<<dim3(8, 64), 256, 0, stream>>>(att, wo_b, bo, x,
        x1, nullptr, nullptr, nullptr, MROWS, D_MODEL, D_MODEL);
    // 6. xn2 = LN2(x1)   (over dead xn)
    ln_kernel<<<MROWS, 256, 0, stream>>>(x1, ln2w, ln2b, xn2);
    // 7/8. FFN in 2 chunks of 4096 rows; final writes fp32 into d_out
    for (int c = 0; c < 2; c++) {
        const bf16*  xc = xn2 + (size_t)c * 4096 * D_MODEL;
        const float* rc = x1  + (size_t)c * 4096 * D_MODEL;
        float*       oc = out + (size_t)c * 4096 * D_MODEL;
        gemm_bt<1,true><<<dim3(32, 32), 256, 0, stream>>>(xc, w1_b, b1, nullptr,
            hid, nullptr, nullptr, nullptr, 4096, DFF, D_MODEL);
        gemm_bt<2,false><<<dim3(8, 32), 256, 0, stream>>>(hid, w2_b, b2, rc,
            oc, nullptr, nullptr, nullptr, 4096, D_MODEL, DFF);
    }
}